// Round 3
// baseline (131.750 us; speedup 1.0000x reference)
//
#include <hip/hip_runtime.h>

typedef float f32x4 __attribute__((ext_vector_type(4)));
typedef short short8 __attribute__((ext_vector_type(8)));
typedef unsigned short ushort8 __attribute__((ext_vector_type(8)));
typedef unsigned short ushort4v __attribute__((ext_vector_type(4)));

// ---------------- workspace layout (ushort elements) ----------------
// WTt ([64 ks][384 r][32 c] bf16, r = mat*128+h): 0 .. 786432
// Q  ([8*2048][128] bf16):        786432
// K  ([8*2048][128] bf16):        2883584
// Vt ([8][128][2048] bf16):       4980736
#define WS_Q  786432
#define WS_K  2883584
#define WS_VT 4980736

__device__ __forceinline__ unsigned short f2bf(float x) {
    unsigned u = __float_as_uint(x);
    u += 0x7FFFu + ((u >> 16) & 1u);      // RNE
    return (unsigned short)(u >> 16);
}

// swizzle for 128-byte rows (attn P buffer)
__device__ __forceinline__ int swz128(int row, int cbyte) {
    return row * 128 + (cbyte ^ ((row & 7) << 4));
}

// ================= K0: W [2048][128] fp32 -> WTt [64 ks][384 r][32 c] =====
__global__ __launch_bounds__(256) void wt_kernel(const float* __restrict__ Wq,
        const float* __restrict__ Wk, const float* __restrict__ Wv,
        unsigned short* __restrict__ ws) {
    __shared__ __align__(16) unsigned short tile[64][136];
    int mat = blockIdx.x >> 5, ct = blockIdx.x & 31;
    const float* W = (mat == 0) ? Wq : ((mat == 1) ? Wk : Wv);
    int cbase = ct * 64;
    int tid = threadIdx.x;
#pragma unroll
    for (int p = 0; p < 8; p++) {
        int fidx = p * 256 + tid;          // float4 index, 2048 total
        int row = fidx >> 5;               // c within tile (0..63)
        int c4 = (fidx & 31) << 2;         // h (0..124)
        float4 v = *(const float4*)&W[(size_t)(cbase + row) * 128 + c4];
        tile[row][c4 + 0] = f2bf(v.x);
        tile[row][c4 + 1] = f2bf(v.y);
        tile[row][c4 + 2] = f2bf(v.z);
        tile[row][c4 + 3] = f2bf(v.w);
    }
    __syncthreads();
    int h = tid >> 1, seg = tid & 1;       // h 0..127, seg = half of 64-col tile
    unsigned short* dst = ws + (ct * 2 + seg) * 12288 + mat * 4096 + h * 32;
#pragma unroll
    for (int q4 = 0; q4 < 4; q4++) {
        ushort8 pk;
#pragma unroll
        for (int e = 0; e < 8; e++) pk[e] = tile[seg * 32 + q4 * 8 + e][h];
        *(ushort8*)(dst + q4 * 8) = pk;
    }
}

// ================= K1: fused QKV projection ===============================
// One block per 64-row m-tile (grid 256 = 1/CU). Tile 64 x 384 (Q|K|V), BK=32,
// 8 waves; wave w owns frag cols {w, 8+w, 16+w} (one Q, one K, one V column).
// Depth-3 pipeline: 3 LDS buffers (A 4KB bf16 + B 24KB), exactly 4 VMEM ops
// per wave per iter (1 x-float4 + 3 B global_load_lds), counted vmcnt(4).
__global__ __launch_bounds__(512, 2) void qkv_kernel(const float* __restrict__ x,
        const float* __restrict__ bq, const float* __restrict__ bk,
        const float* __restrict__ bv, unsigned short* __restrict__ ws) {
    __shared__ __align__(16) char lds_raw[3 * 28672];     // 84 KB
    int mt = blockIdx.x;                 // 0..255
    const unsigned short* WTt = ws;
    const float* x0 = x + (size_t)mt * 64 * 2048;
    int tid = threadIdx.x, lane = tid & 63, w = tid >> 6;
    int lr = lane & 15, lg = lane >> 4;

    // bias: load + force completion BEFORE any pipelined VMEM (keeps counts exact)
    int hme = w * 16 + lr;
    float bb0 = bq[hme], bb1 = bk[hme], bb2 = bv[hme];
    asm volatile("" : "+v"(bb0), "+v"(bb1), "+v"(bb2));
    asm volatile("s_waitcnt vmcnt(0)" ::: "memory");

    // ---- A staging geometry: thread owns 1 float4 of the 64x32 x-tile ----
    int rowA = tid >> 3, kk = tid & 7;               // rowA 0..63, kk: 8B slot
    const float* aSrc = x0 + (size_t)rowA * 2048 + kk * 4;
    int aDst = rowA * 64 + (((kk >> 1) ^ (rowA & 3)) << 4) + ((kk & 1) << 3);

    // ---- B staging geometry: 3 global_load_lds per thread per iter -------
    // chunk c = j*8 + w covers LDS bytes [c*1024, c*1024+1024); lane l holds
    // 16B slot sigma = c*64 + l -> row r = sigma>>2, phys slot p = sigma&3,
    // logical slot s = p ^ (r&3); source elem = r*32 + s*8 (pre-swizzled).
    int bOffG[3], bDstC[3];
#pragma unroll
    for (int j = 0; j < 3; j++) {
        int c = j * 8 + w;
        int r = c * 16 + (lane >> 2);
        int s = (lane & 3) ^ (r & 3);
        bOffG[j] = r * 32 + s * 8;
        bDstC[j] = c * 1024;
    }

    // ---- fragment read offsets (bytes within buffer) ----
    int xorT = (lg ^ (lr & 3)) << 4;
    int aOff[4], bOff[3];
#pragma unroll
    for (int i = 0; i < 4; i++) aOff[i] = (i * 16 + lr) * 64 + xorT;
#pragma unroll
    for (int j = 0; j < 3; j++) bOff[j] = ((j * 8 + w) * 16 + lr) * 64 + xorT;

    f32x4 acc[4][3];
#pragma unroll
    for (int i = 0; i < 4; i++)
#pragma unroll
        for (int j = 0; j < 3; j++) acc[i][j] = (f32x4){0.f, 0.f, 0.f, 0.f};
    float4 rA[2];

#define ISSUE_A(T) do { rA[(T) & 1] = *(const float4*)(aSrc + (size_t)(T) * 32); } while (0)
#define ISSUE_B(BUF, T) do { \
        const unsigned short* bs_ = WTt + (size_t)(T) * 12288; \
        char* bd_ = lds_raw + (BUF) * 28672 + 4096; \
        __builtin_amdgcn_global_load_lds((const __attribute__((address_space(1))) unsigned*)(bs_ + bOffG[0]), \
            (__attribute__((address_space(3))) unsigned*)(bd_ + bDstC[0]), 16, 0, 0); \
        __builtin_amdgcn_global_load_lds((const __attribute__((address_space(1))) unsigned*)(bs_ + bOffG[1]), \
            (__attribute__((address_space(3))) unsigned*)(bd_ + bDstC[1]), 16, 0, 0); \
        __builtin_amdgcn_global_load_lds((const __attribute__((address_space(1))) unsigned*)(bs_ + bOffG[2]), \
            (__attribute__((address_space(3))) unsigned*)(bd_ + bDstC[2]), 16, 0, 0); \
    } while (0)
#define WRITE_A(T, BUF) do { \
        const float* f_ = (const float*)&rA[(T) & 1]; \
        ushort4v pk_; \
        pk_[0] = f2bf(f_[0]); pk_[1] = f2bf(f_[1]); pk_[2] = f2bf(f_[2]); pk_[3] = f2bf(f_[3]); \
        *(ushort4v*)(lds_raw + (BUF) * 28672 + aDst) = pk_; \
    } while (0)

    // body: read frags(T) | issue grp(T+2) | MFMA | vmcnt | ds_write A(T+1) | bar
#define QKV_BODY(U, T, STAGE, WRITE, BAR) do { \
        const char* Ab_ = lds_raw + (U) * 28672; \
        const char* Bb_ = Ab_ + 4096; \
        short8 av0 = *(const short8*)(Ab_ + aOff[0]); \
        short8 av1 = *(const short8*)(Ab_ + aOff[1]); \
        short8 av2 = *(const short8*)(Ab_ + aOff[2]); \
        short8 av3 = *(const short8*)(Ab_ + aOff[3]); \
        short8 bv0 = *(const short8*)(Bb_ + bOff[0]); \
        short8 bv1 = *(const short8*)(Bb_ + bOff[1]); \
        short8 bv2 = *(const short8*)(Bb_ + bOff[2]); \
        if (STAGE) { ISSUE_A((T) + 2); ISSUE_B(((U) + 2) % 3, (T) + 2); } \
        acc[0][0] = __builtin_amdgcn_mfma_f32_16x16x32_bf16(av0, bv0, acc[0][0], 0, 0, 0); \
        acc[1][0] = __builtin_amdgcn_mfma_f32_16x16x32_bf16(av1, bv0, acc[1][0], 0, 0, 0); \
        acc[2][0] = __builtin_amdgcn_mfma_f32_16x16x32_bf16(av2, bv0, acc[2][0], 0, 0, 0); \
        acc[3][0] = __builtin_amdgcn_mfma_f32_16x16x32_bf16(av3, bv0, acc[3][0], 0, 0, 0); \
        acc[0][1] = __builtin_amdgcn_mfma_f32_16x16x32_bf16(av0, bv1, acc[0][1], 0, 0, 0); \
        acc[1][1] = __builtin_amdgcn_mfma_f32_16x16x32_bf16(av1, bv1, acc[1][1], 0, 0, 0); \
        acc[2][1] = __builtin_amdgcn_mfma_f32_16x16x32_bf16(av2, bv1, acc[2][1], 0, 0, 0); \
        acc[3][1] = __builtin_amdgcn_mfma_f32_16x16x32_bf16(av3, bv1, acc[3][1], 0, 0, 0); \
        acc[0][2] = __builtin_amdgcn_mfma_f32_16x16x32_bf16(av0, bv2, acc[0][2], 0, 0, 0); \
        acc[1][2] = __builtin_amdgcn_mfma_f32_16x16x32_bf16(av1, bv2, acc[1][2], 0, 0, 0); \
        acc[2][2] = __builtin_amdgcn_mfma_f32_16x16x32_bf16(av2, bv2, acc[2][2], 0, 0, 0); \
        acc[3][2] = __builtin_amdgcn_mfma_f32_16x16x32_bf16(av3, bv2, acc[3][2], 0, 0, 0); \
        if (STAGE) { asm volatile("s_waitcnt vmcnt(4)" ::: "memory"); } \
        else if (WRITE) { asm volatile("s_waitcnt vmcnt(0)" ::: "memory"); } \
        if (WRITE) { \
            WRITE_A((T) + 1, ((U) + 1) % 3); \
            asm volatile("s_waitcnt lgkmcnt(0)" ::: "memory"); \
        } \
        if (BAR) __builtin_amdgcn_s_barrier(); \
    } while (0)

    // prologue: groups 0 and 1 in flight, tile 0 staged
    ISSUE_A(0); ISSUE_B(0, 0);
    ISSUE_A(1); ISSUE_B(1, 1);
    asm volatile("s_waitcnt vmcnt(4)" ::: "memory");   // group 0 landed
    WRITE_A(0, 0);
    asm volatile("s_waitcnt lgkmcnt(0)" ::: "memory");
    __builtin_amdgcn_s_barrier();

    for (int t3 = 0; t3 < 20; t3++) {
        int T0 = t3 * 3;
        QKV_BODY(0, T0 + 0, true, true, true);
        QKV_BODY(1, T0 + 1, true, true, true);
        QKV_BODY(2, T0 + 2, true, true, true);
    }
    QKV_BODY(0, 60, true,  true,  true);
    QKV_BODY(1, 61, true,  true,  true);
    QKV_BODY(2, 62, false, true,  true);
    QKV_BODY(0, 63, false, false, false);

    // ----- epilogue -----
    __syncthreads();   // all frag reads done before LDS reuse
    unsigned short* qout = ws + WS_Q;
    unsigned short* kout = ws + WS_K;
    const float sc = 0.08838834764831845f;             // H^-0.5 folded into Q
#pragma unroll
    for (int i = 0; i < 4; i++)
#pragma unroll
        for (int r = 0; r < 4; r++) {
            size_t t = (size_t)mt * 64 + i * 16 + (lg << 2) + r;
            qout[t * 128 + hme] = f2bf((acc[i][0][r] + bb0) * sc);
            kout[t * 128 + hme] = f2bf(acc[i][1][r] + bb1);
        }
    // V: transpose through LDS -> Vt[h][t]
    unsigned short* vt_sm = (unsigned short*)lds_raw;  // [64 t][136 h]
#pragma unroll
    for (int i = 0; i < 4; i++)
#pragma unroll
        for (int r = 0; r < 4; r++)
            vt_sm[(i * 16 + (lg << 2) + r) * 136 + hme] = f2bf(acc[i][2][r] + bb2);
    __syncthreads();
    int h2 = tid >> 2, q4 = tid & 3;
    unsigned short* vdst = ws + WS_VT + ((size_t)(mt >> 5) * 128 + h2) * 2048
                           + (mt & 31) * 64 + q4 * 16;
    ushort8 pk0, pk1;
#pragma unroll
    for (int e = 0; e < 8; e++) {
        pk0[e] = vt_sm[(q4 * 16 + e) * 136 + h2];
        pk1[e] = vt_sm[(q4 * 16 + 8 + e) * 136 + h2];
    }
    *(ushort8*)vdst = pk0;
    *(ushort8*)(vdst + 8) = pk1;
#undef QKV_BODY
#undef WRITE_A
#undef ISSUE_B
#undef ISSUE_A
}

// ================= K2: causal flash attention (unchanged) =================
__global__ __launch_bounds__(256, 2) void attn_kernel(const unsigned short* __restrict__ ws,
        float* __restrict__ out) {
    __shared__ __align__(16) float o_lds[4][32][128];   // 64 KB
    __shared__ float ml[4][2][32];
    int b = blockIdx.x;
    int qi = 63 - (int)blockIdx.y;          // longest blocks first
    int qbase = qi * 32;
    int tid = threadIdx.x, lane = tid & 63, w = tid >> 6;
    int lr = lane & 15, lg = lane >> 4;
    const unsigned short* Qb = ws + WS_Q + (size_t)b * 2048 * 128;
    const unsigned short* Kb = ws + WS_K + (size_t)b * 2048 * 128;
    const unsigned short* Vt = ws + WS_VT + (size_t)b * 128 * 2048;
    char* p_lds = (char*)&o_lds[w][0][0];   // per-wave private 4 KB

    short8 qf[2][4];
#pragma unroll
    for (int i = 0; i < 2; i++)
#pragma unroll
        for (int kf = 0; kf < 4; kf++)
            qf[i][kf] = *(const short8*)&Qb[(size_t)(qbase + i * 16 + lr) * 128 + kf * 32 + lg * 8];

    f32x4 o[2][8];
#pragma unroll
    for (int i = 0; i < 2; i++)
#pragma unroll
        for (int jn = 0; jn < 8; jn++) o[i][jn] = (f32x4){0.f, 0.f, 0.f, 0.f};
    float mrow[2][4], lrow[2][4];
#pragma unroll
    for (int i = 0; i < 2; i++)
#pragma unroll
        for (int r = 0; r < 4; r++) { mrow[i][r] = -__builtin_inff(); lrow[i][r] = 0.f; }

    int ntiles = qi / 2 + 1;
    for (int ti = w; ti < ntiles; ti += 4) {
        int sb = ti * 64;
        f32x4 s[2][4];
#pragma unroll
        for (int i = 0; i < 2; i++)
#pragma unroll
            for (int nf = 0; nf < 4; nf++) s[i][nf] = (f32x4){0.f, 0.f, 0.f, 0.f};
        {
            short8 kb[4][4];
#pragma unroll
            for (int nf = 0; nf < 4; nf++)
#pragma unroll
                for (int kf = 0; kf < 4; kf++)
                    kb[nf][kf] = *(const short8*)&Kb[(size_t)(sb + nf * 16 + lr) * 128 + kf * 32 + lg * 8];
#pragma unroll
            for (int kf = 0; kf < 4; kf++)
#pragma unroll
                for (int i = 0; i < 2; i++)
#pragma unroll
                    for (int nf = 0; nf < 4; nf++)
                        s[i][nf] = __builtin_amdgcn_mfma_f32_16x16x32_bf16(qf[i][kf], kb[nf][kf], s[i][nf], 0, 0, 0);
        }
        if (sb + 63 > qbase) {   // diagonal tile(s): causal mask
#pragma unroll
            for (int i = 0; i < 2; i++)
#pragma unroll
                for (int nf = 0; nf < 4; nf++)
#pragma unroll
                    for (int r = 0; r < 4; r++) {
                        int sg = sb + nf * 16 + lr;
                        int qg = qbase + i * 16 + (lg << 2) + r;
                        if (sg > qg) s[i][nf][r] = -__builtin_inff();
                    }
        }
        float alpha[2][4];
#pragma unroll
        for (int i = 0; i < 2; i++)
#pragma unroll
            for (int r = 0; r < 4; r++) {
                float pm = fmaxf(fmaxf(s[i][0][r], s[i][1][r]), fmaxf(s[i][2][r], s[i][3][r]));
                pm = fmaxf(pm, __shfl_xor(pm, 1));
                pm = fmaxf(pm, __shfl_xor(pm, 2));
                pm = fmaxf(pm, __shfl_xor(pm, 4));
                pm = fmaxf(pm, __shfl_xor(pm, 8));
                float mn = fmaxf(mrow[i][r], pm);
                alpha[i][r] = __expf(mrow[i][r] - mn);
                mrow[i][r] = mn;
            }
#pragma unroll
        for (int i = 0; i < 2; i++)
#pragma unroll
            for (int r = 0; r < 4; r++) {
                float rs = 0.f;
#pragma unroll
                for (int nf = 0; nf < 4; nf++) {
                    float p = __expf(s[i][nf][r] - mrow[i][r]);
                    s[i][nf][r] = p;
                    rs += p;
                }
                rs += __shfl_xor(rs, 1);
                rs += __shfl_xor(rs, 2);
                rs += __shfl_xor(rs, 4);
                rs += __shfl_xor(rs, 8);
                lrow[i][r] = lrow[i][r] * alpha[i][r] + rs;
            }
#pragma unroll
        for (int i = 0; i < 2; i++)
#pragma unroll
            for (int jn = 0; jn < 8; jn++)
#pragma unroll
                for (int r = 0; r < 4; r++) o[i][jn][r] *= alpha[i][r];
#pragma unroll
        for (int i = 0; i < 2; i++)
#pragma unroll
            for (int nf = 0; nf < 4; nf++)
#pragma unroll
                for (int r = 0; r < 4; r++) {
                    int row = i * 16 + (lg << 2) + r;
                    int cb2 = (nf * 16 + lr) * 2;
                    *(unsigned short*)(p_lds + swz128(row, cb2)) = f2bf(s[i][nf][r]);
                }
        asm volatile("s_waitcnt lgkmcnt(0)" ::: "memory");
        short8 pa[2][2];
#pragma unroll
        for (int i = 0; i < 2; i++)
#pragma unroll
            for (int kf = 0; kf < 2; kf++)
                pa[i][kf] = *(const short8*)(p_lds + swz128(i * 16 + lr, kf * 64 + lg * 16));
        short8 vb[8][2];
#pragma unroll
        for (int nf = 0; nf < 8; nf++)
#pragma unroll
            for (int kf = 0; kf < 2; kf++)
                vb[nf][kf] = *(const short8*)&Vt[(size_t)(nf * 16 + lr) * 2048 + sb + kf * 32 + lg * 8];
#pragma unroll
        for (int i = 0; i < 2; i++)
#pragma unroll
            for (int nf = 0; nf < 8; nf++)
#pragma unroll
                for (int kf = 0; kf < 2; kf++)
                    o[i][nf] = __builtin_amdgcn_mfma_f32_16x16x32_bf16(pa[i][kf], vb[nf][kf], o[i][nf], 0, 0, 0);
    }
#pragma unroll
    for (int i = 0; i < 2; i++)
#pragma unroll
        for (int r = 0; r < 4; r++) {
            int q = i * 16 + (lg << 2) + r;
            ml[w][0][q] = mrow[i][r];
            ml[w][1][q] = lrow[i][r];
        }
    asm volatile("s_waitcnt lgkmcnt(0)" ::: "memory");
#pragma unroll
    for (int i = 0; i < 2; i++)
#pragma unroll
        for (int jn = 0; jn < 8; jn++)
#pragma unroll
            for (int r = 0; r < 4; r++)
                o_lds[w][i * 16 + (lg << 2) + r][jn * 16 + lr] = o[i][jn][r];
    __syncthreads();
    int q = tid >> 3, h0 = (tid & 7) << 4;
    float mg = fmaxf(fmaxf(ml[0][0][q], ml[1][0][q]), fmaxf(ml[2][0][q], ml[3][0][q]));
    float scw[4], den = 0.f;
#pragma unroll
    for (int w4 = 0; w4 < 4; w4++) {
        scw[w4] = __expf(ml[w4][0][q] - mg);
        den += scw[w4] * ml[w4][1][q];
    }
    float inv = 1.0f / den;
    float* op = out + ((size_t)b * 2048 + qbase + q) * 128 + h0;
#pragma unroll
    for (int jj = 0; jj < 4; jj++) {
        f32x4 a4 = (f32x4){0.f, 0.f, 0.f, 0.f};
#pragma unroll
        for (int w4 = 0; w4 < 4; w4++) {
            f32x4 v = *(const f32x4*)&o_lds[w4][q][h0 + jj * 4];
            a4 += scw[w4] * v;
        }
        a4 *= inv;
        *(f32x4*)(op + jj * 4) = a4;
    }
}

extern "C" void kernel_launch(void* const* d_in, const int* in_sizes, int n_in,
                              void* d_out, int out_size, void* d_ws, size_t ws_size,
                              hipStream_t stream) {
    (void)in_sizes; (void)n_in; (void)out_size; (void)ws_size;
    const float* x  = (const float*)d_in[0];
    const float* Wq = (const float*)d_in[1];
    const float* bq = (const float*)d_in[2];
    const float* Wk = (const float*)d_in[3];
    const float* bk = (const float*)d_in[4];
    const float* Wv = (const float*)d_in[5];
    const float* bv = (const float*)d_in[6];
    unsigned short* ws = (unsigned short*)d_ws;
    float* out = (float*)d_out;

    wt_kernel<<<96, 256, 0, stream>>>(Wq, Wk, Wv, ws);
    qkv_kernel<<<256, 512, 0, stream>>>(x, bq, bk, bv, ws);
    attn_kernel<<<dim3(8, 64), 256, 0, stream>>>(ws, out);
}

// Round 4
// 106.880 us; speedup vs baseline: 1.2327x; 1.2327x over previous
//
#include <hip/hip_runtime.h>

typedef float f32x4 __attribute__((ext_vector_type(4)));
typedef short short8 __attribute__((ext_vector_type(8)));
typedef unsigned short ushort8 __attribute__((ext_vector_type(8)));

// ---------------- workspace layout (ushort elements) ----------------
// WTt (3 x [64 ks][128 h][32 c] bf16): 0 .. 786432
// Q  ([8*2048][128] bf16):        786432
// K  ([8*2048][128] bf16):        2883584
// Vt ([8][128][2048] bf16):       4980736
#define WS_Q  786432
#define WS_K  2883584
#define WS_VT 4980736

__device__ __forceinline__ unsigned short f2bf(float x) {
    unsigned u = __float_as_uint(x);
    u += 0x7FFFu + ((u >> 16) & 1u);      // RNE
    return (unsigned short)(u >> 16);
}

// swizzle for 128-byte rows (attn P buffer)
__device__ __forceinline__ int swz128(int row, int cbyte) {
    return row * 128 + (cbyte ^ ((row & 7) << 4));
}

// ================= K0: W [2048][128] fp32 -> WTt [64 ks][128 h][32 c] bf16
__global__ __launch_bounds__(256) void wt_kernel(const float* __restrict__ Wq,
        const float* __restrict__ Wk, const float* __restrict__ Wv,
        unsigned short* __restrict__ ws) {
    __shared__ __align__(16) unsigned short tile[64][136];
    int mat = blockIdx.x >> 5, ct = blockIdx.x & 31;
    const float* W = (mat == 0) ? Wq : ((mat == 1) ? Wk : Wv);
    int cbase = ct * 64;
    int tid = threadIdx.x;
#pragma unroll
    for (int p = 0; p < 8; p++) {
        int fidx = p * 256 + tid;          // float4 index, 2048 total
        int row = fidx >> 5;               // c within tile (0..63)
        int c4 = (fidx & 31) << 2;         // h (0..124)
        float4 v = *(const float4*)&W[(size_t)(cbase + row) * 128 + c4];
        tile[row][c4 + 0] = f2bf(v.x);
        tile[row][c4 + 1] = f2bf(v.y);
        tile[row][c4 + 2] = f2bf(v.z);
        tile[row][c4 + 3] = f2bf(v.w);
    }
    __syncthreads();
    int h = tid >> 1, seg = tid & 1;
    unsigned short* dst = ws + mat * 262144 + (ct * 2 + seg) * 4096 + h * 32;
#pragma unroll
    for (int q4 = 0; q4 < 4; q4++) {
        ushort8 pk;
#pragma unroll
        for (int e = 0; e < 8; e++) pk[e] = tile[seg * 32 + q4 * 8 + e][h];
        *(ushort8*)(dst + q4 * 8) = pk;
    }
}

// ================= K1: QKV projection, depth-4 pipelined ==================
// M=64 N=128 BK=32; 4 LDS buffers (48KB -> 3 blocks/CU); group T = 4 VMEM ops
// (2 x-float4 + 2 B global_load_lds). Body T issues group T+3 and waits
// vmcnt(8) => group T+1 landed, 2 full iterations of latency in flight.
__global__ __launch_bounds__(256, 3) void qkv_kernel(const float* __restrict__ x,
        const float* __restrict__ bq, const float* __restrict__ bk,
        const float* __restrict__ bv, unsigned short* __restrict__ ws) {
    __shared__ __align__(16) unsigned short lds[4][6144];   // 4 x (A 4KB | B 8KB)
    int bid = blockIdx.x;
    int g = bid / 24, j = bid - g * 24;
    int which = j >> 3;                 // 0=Q 1=K 2=V (3 blocks of one mt share XCD)
    int mt = g * 8 + (j & 7);           // 0..255
    const unsigned short* WTt = ws + which * 262144;
    const float* x0 = x + (size_t)mt * 64 * 2048;
    int tid = threadIdx.x, lane = tid & 63, wid = tid >> 6;
    int lr = lane & 15, lg = lane >> 4;
    int m0 = (wid >> 1) * 32, n0 = (wid & 1) * 64;

    // bias loads drained before the pipeline so vmcnt counts stay exact
    const float* bias = (which == 0) ? bq : ((which == 1) ? bk : bv);
    float bb[4];
#pragma unroll
    for (int j2 = 0; j2 < 4; j2++) bb[j2] = bias[n0 + j2 * 16 + lr];
    asm volatile("" : "+v"(bb[0]), "+v"(bb[1]), "+v"(bb[2]), "+v"(bb[3]));
    asm volatile("s_waitcnt vmcnt(0)" ::: "memory");

    // A staging geometry (reg-staged): thread owns 8 floats of the 64x32 tile
    int rowA = tid >> 2, ca = tid & 3;
    const float* aSrc = x0 + (size_t)rowA * 2048 + ca * 8;
    int aDst = rowA * 64 + ((ca ^ ((rowA >> 1) & 3)) << 4);   // swizzled byte off

    // B staging geometry (DMA): 2 issues/wave, 1KB each, pre-swizzled source
    int bsrc0, bsrc1, bdst0, bdst1;
    {
        int idx0 = (0 * 4 + wid) * 64 + lane;
        int h0 = idx0 >> 2, c0 = idx0 & 3;
        bsrc0 = h0 * 32 + ((c0 ^ ((h0 >> 1) & 3)) << 3);
        bdst0 = (0 * 4 + wid) * 1024;
        int idx1 = (1 * 4 + wid) * 64 + lane;
        int h1 = idx1 >> 2, c1 = idx1 & 3;
        bsrc1 = h1 * 32 + ((c1 ^ ((h1 >> 1) & 3)) << 3);
        bdst1 = (1 * 4 + wid) * 1024;
    }

    // fragment read offsets (bytes, swizzled)
    int aOff0, aOff1, bOff0, bOff1, bOff2, bOff3;
    {
        int r0 = m0 + 0 * 16 + lr; aOff0 = r0 * 64 + ((lg ^ ((r0 >> 1) & 3)) << 4);
        int r1 = m0 + 1 * 16 + lr; aOff1 = r1 * 64 + ((lg ^ ((r1 >> 1) & 3)) << 4);
        int s0 = n0 + 0 * 16 + lr; bOff0 = s0 * 64 + ((lg ^ ((s0 >> 1) & 3)) << 4);
        int s1 = n0 + 1 * 16 + lr; bOff1 = s1 * 64 + ((lg ^ ((s1 >> 1) & 3)) << 4);
        int s2 = n0 + 2 * 16 + lr; bOff2 = s2 * 64 + ((lg ^ ((s2 >> 1) & 3)) << 4);
        int s3 = n0 + 3 * 16 + lr; bOff3 = s3 * 64 + ((lg ^ ((s3 >> 1) & 3)) << 4);
    }

    f32x4 acc[2][4];
#pragma unroll
    for (int i = 0; i < 2; i++)
#pragma unroll
        for (int j3 = 0; j3 < 4; j3++) acc[i][j3] = (f32x4){0.f, 0.f, 0.f, 0.f};
    float4 rA[4][2];   // 4 statically-indexed in-flight A slots

#define ISSUE_A(SLOT, T) do { \
        const float* ap_ = aSrc + (size_t)(T) * 32; \
        rA[SLOT][0] = *(const float4*)ap_; \
        rA[SLOT][1] = *(const float4*)(ap_ + 4); \
    } while (0)
#define ISSUE_B(BUF, T) do { \
        const unsigned short* bs_ = WTt + (size_t)(T) * 4096; \
        char* bd_ = (char*)&lds[BUF][2048]; \
        __builtin_amdgcn_global_load_lds((const __attribute__((address_space(1))) unsigned*)(bs_ + bsrc0), \
            (__attribute__((address_space(3))) unsigned*)(bd_ + bdst0), 16, 0, 0); \
        __builtin_amdgcn_global_load_lds((const __attribute__((address_space(1))) unsigned*)(bs_ + bsrc1), \
            (__attribute__((address_space(3))) unsigned*)(bd_ + bdst1), 16, 0, 0); \
    } while (0)
#define WRITE_A(SLOT, BUF) do { \
        const float* f_ = (const float*)&rA[SLOT][0]; \
        ushort8 pk_; \
        pk_[0] = f2bf(f_[0]); pk_[1] = f2bf(f_[1]); pk_[2] = f2bf(f_[2]); pk_[3] = f2bf(f_[3]); \
        pk_[4] = f2bf(f_[4]); pk_[5] = f2bf(f_[5]); pk_[6] = f2bf(f_[6]); pk_[7] = f2bf(f_[7]); \
        *(ushort8*)((char*)&lds[BUF][0] + aDst) = pk_; \
    } while (0)

    // body(T): frags(T) | issue grp(T+3) | MFMA | wait | ds_write A(T+1) | bar
    // steady: vmcnt(8) = grp T+1 landed (T+2,T+3 in flight).  tail: 4, then 0.
#define QKV_BODY(U, T, STAGE, WAIT4, WAIT0, WRITE, BAR) do { \
        const char* Ab_ = (const char*)&lds[U][0]; \
        const char* Bb_ = (const char*)&lds[U][2048]; \
        short8 av0 = *(const short8*)(Ab_ + aOff0); \
        short8 av1 = *(const short8*)(Ab_ + aOff1); \
        short8 bv0 = *(const short8*)(Bb_ + bOff0); \
        short8 bv1 = *(const short8*)(Bb_ + bOff1); \
        short8 bv2 = *(const short8*)(Bb_ + bOff2); \
        short8 bv3 = *(const short8*)(Bb_ + bOff3); \
        if (STAGE) { ISSUE_A(((T) + 3) & 3, (T) + 3); ISSUE_B(((U) + 3) & 3, (T) + 3); } \
        acc[0][0] = __builtin_amdgcn_mfma_f32_16x16x32_bf16(av0, bv0, acc[0][0], 0, 0, 0); \
        acc[0][1] = __builtin_amdgcn_mfma_f32_16x16x32_bf16(av0, bv1, acc[0][1], 0, 0, 0); \
        acc[0][2] = __builtin_amdgcn_mfma_f32_16x16x32_bf16(av0, bv2, acc[0][2], 0, 0, 0); \
        acc[0][3] = __builtin_amdgcn_mfma_f32_16x16x32_bf16(av0, bv3, acc[0][3], 0, 0, 0); \
        acc[1][0] = __builtin_amdgcn_mfma_f32_16x16x32_bf16(av1, bv0, acc[1][0], 0, 0, 0); \
        acc[1][1] = __builtin_amdgcn_mfma_f32_16x16x32_bf16(av1, bv1, acc[1][1], 0, 0, 0); \
        acc[1][2] = __builtin_amdgcn_mfma_f32_16x16x32_bf16(av1, bv2, acc[1][2], 0, 0, 0); \
        acc[1][3] = __builtin_amdgcn_mfma_f32_16x16x32_bf16(av1, bv3, acc[1][3], 0, 0, 0); \
        if (STAGE)      { asm volatile("s_waitcnt vmcnt(8)" ::: "memory"); } \
        else if (WAIT4) { asm volatile("s_waitcnt vmcnt(4)" ::: "memory"); } \
        else if (WAIT0) { asm volatile("s_waitcnt vmcnt(0)" ::: "memory"); } \
        if (WRITE) { \
            WRITE_A(((T) + 1) & 3, ((U) + 1) & 3); \
            asm volatile("s_waitcnt lgkmcnt(0)" ::: "memory"); \
        } \
        if (BAR) __builtin_amdgcn_s_barrier(); \
    } while (0)

    // prologue: groups 0,1,2 in flight; tile 0's A written
    ISSUE_A(0, 0); ISSUE_B(0, 0);
    ISSUE_A(1, 1); ISSUE_B(1, 1);
    ISSUE_A(2, 2); ISSUE_B(2, 2);
    asm volatile("s_waitcnt vmcnt(8)" ::: "memory");   // group 0 landed
    WRITE_A(0, 0);
    asm volatile("s_waitcnt lgkmcnt(0)" ::: "memory");
    __builtin_amdgcn_s_barrier();

    for (int to = 0; to < 15; to++) {
        int T0 = to * 4;
        QKV_BODY(0, T0 + 0, true, false, false, true, true);
        QKV_BODY(1, T0 + 1, true, false, false, true, true);
        QKV_BODY(2, T0 + 2, true, false, false, true, true);
        QKV_BODY(3, T0 + 3, true, false, false, true, true);
    }
    QKV_BODY(0, 60, true,  false, false, true,  true);   // issues grp 63
    QKV_BODY(1, 61, false, true,  false, true,  true);   // grp 62 landed
    QKV_BODY(2, 62, false, false, true,  true,  true);   // grp 63 landed
    QKV_BODY(3, 63, false, false, false, false, false);

    // ----- epilogue -----
    if (which < 2) {
        unsigned short* outp = ws + ((which == 0) ? WS_Q : WS_K);
        float sc = (which == 0) ? 0.08838834764831845f : 1.0f;
#pragma unroll
        for (int i = 0; i < 2; i++)
#pragma unroll
            for (int j3 = 0; j3 < 4; j3++) {
                int h = n0 + j3 * 16 + lr;
#pragma unroll
                for (int r = 0; r < 4; r++) {
                    int t = mt * 64 + m0 + i * 16 + (lg << 2) + r;
                    outp[(size_t)t * 128 + h] = f2bf((acc[i][j3][r] + bb[j3]) * sc);
                }
            }
    } else {
        __syncthreads();
        unsigned short* sm = &lds[0][0];   // [64][136]
#pragma unroll
        for (int i = 0; i < 2; i++)
#pragma unroll
            for (int j3 = 0; j3 < 4; j3++) {
                int h = n0 + j3 * 16 + lr;
#pragma unroll
                for (int r = 0; r < 4; r++) {
                    int tl = m0 + i * 16 + (lg << 2) + r;
                    sm[tl * 136 + h] = f2bf(acc[i][j3][r] + bb[j3]);
                }
            }
        __syncthreads();
        int h = tid & 127, seg = tid >> 7;
        int b2 = mt >> 5;
        int tin = (mt & 31) * 64 + seg * 32;
        unsigned short* vt = ws + WS_VT + ((size_t)b2 * 128 + h) * 2048 + tin;
#pragma unroll
        for (int q4 = 0; q4 < 4; q4++) {
            ushort8 pk;
#pragma unroll
            for (int e = 0; e < 8; e++) pk[e] = sm[(seg * 32 + q4 * 8 + e) * 136 + h];
            *(ushort8*)(vt + q4 * 8) = pk;
        }
    }
#undef QKV_BODY
#undef WRITE_A
#undef ISSUE_B
#undef ISSUE_A
}

// ================= K2: causal flash attention (unchanged) =================
__global__ __launch_bounds__(256, 2) void attn_kernel(const unsigned short* __restrict__ ws,
        float* __restrict__ out) {
    __shared__ __align__(16) float o_lds[4][32][128];   // 64 KB
    __shared__ float ml[4][2][32];
    int b = blockIdx.x;
    int qi = 63 - (int)blockIdx.y;          // longest blocks first
    int qbase = qi * 32;
    int tid = threadIdx.x, lane = tid & 63, w = tid >> 6;
    int lr = lane & 15, lg = lane >> 4;
    const unsigned short* Qb = ws + WS_Q + (size_t)b * 2048 * 128;
    const unsigned short* Kb = ws + WS_K + (size_t)b * 2048 * 128;
    const unsigned short* Vt = ws + WS_VT + (size_t)b * 128 * 2048;
    char* p_lds = (char*)&o_lds[w][0][0];   // per-wave private 4 KB

    short8 qf[2][4];
#pragma unroll
    for (int i = 0; i < 2; i++)
#pragma unroll
        for (int kf = 0; kf < 4; kf++)
            qf[i][kf] = *(const short8*)&Qb[(size_t)(qbase + i * 16 + lr) * 128 + kf * 32 + lg * 8];

    f32x4 o[2][8];
#pragma unroll
    for (int i = 0; i < 2; i++)
#pragma unroll
        for (int jn = 0; jn < 8; jn++) o[i][jn] = (f32x4){0.f, 0.f, 0.f, 0.f};
    float mrow[2][4], lrow[2][4];
#pragma unroll
    for (int i = 0; i < 2; i++)
#pragma unroll
        for (int r = 0; r < 4; r++) { mrow[i][r] = -__builtin_inff(); lrow[i][r] = 0.f; }

    int ntiles = qi / 2 + 1;
    for (int ti = w; ti < ntiles; ti += 4) {
        int sb = ti * 64;
        f32x4 s[2][4];
#pragma unroll
        for (int i = 0; i < 2; i++)
#pragma unroll
            for (int nf = 0; nf < 4; nf++) s[i][nf] = (f32x4){0.f, 0.f, 0.f, 0.f};
        {
            short8 kb[4][4];
#pragma unroll
            for (int nf = 0; nf < 4; nf++)
#pragma unroll
                for (int kf = 0; kf < 4; kf++)
                    kb[nf][kf] = *(const short8*)&Kb[(size_t)(sb + nf * 16 + lr) * 128 + kf * 32 + lg * 8];
#pragma unroll
            for (int kf = 0; kf < 4; kf++)
#pragma unroll
                for (int i = 0; i < 2; i++)
#pragma unroll
                    for (int nf = 0; nf < 4; nf++)
                        s[i][nf] = __builtin_amdgcn_mfma_f32_16x16x32_bf16(qf[i][kf], kb[nf][kf], s[i][nf], 0, 0, 0);
        }
        if (sb + 63 > qbase) {   // diagonal tile(s): causal mask
#pragma unroll
            for (int i = 0; i < 2; i++)
#pragma unroll
                for (int nf = 0; nf < 4; nf++)
#pragma unroll
                    for (int r = 0; r < 4; r++) {
                        int sg = sb + nf * 16 + lr;
                        int qg = qbase + i * 16 + (lg << 2) + r;
                        if (sg > qg) s[i][nf][r] = -__builtin_inff();
                    }
        }
        float alpha[2][4];
#pragma unroll
        for (int i = 0; i < 2; i++)
#pragma unroll
            for (int r = 0; r < 4; r++) {
                float pm = fmaxf(fmaxf(s[i][0][r], s[i][1][r]), fmaxf(s[i][2][r], s[i][3][r]));
                pm = fmaxf(pm, __shfl_xor(pm, 1));
                pm = fmaxf(pm, __shfl_xor(pm, 2));
                pm = fmaxf(pm, __shfl_xor(pm, 4));
                pm = fmaxf(pm, __shfl_xor(pm, 8));
                float mn = fmaxf(mrow[i][r], pm);
                alpha[i][r] = __expf(mrow[i][r] - mn);
                mrow[i][r] = mn;
            }
#pragma unroll
        for (int i = 0; i < 2; i++)
#pragma unroll
            for (int r = 0; r < 4; r++) {
                float rs = 0.f;
#pragma unroll
                for (int nf = 0; nf < 4; nf++) {
                    float p = __expf(s[i][nf][r] - mrow[i][r]);
                    s[i][nf][r] = p;
                    rs += p;
                }
                rs += __shfl_xor(rs, 1);
                rs += __shfl_xor(rs, 2);
                rs += __shfl_xor(rs, 4);
                rs += __shfl_xor(rs, 8);
                lrow[i][r] = lrow[i][r] * alpha[i][r] + rs;
            }
#pragma unroll
        for (int i = 0; i < 2; i++)
#pragma unroll
            for (int jn = 0; jn < 8; jn++)
#pragma unroll
                for (int r = 0; r < 4; r++) o[i][jn][r] *= alpha[i][r];
#pragma unroll
        for (int i = 0; i < 2; i++)
#pragma unroll
            for (int nf = 0; nf < 4; nf++)
#pragma unroll
                for (int r = 0; r < 4; r++) {
                    int row = i * 16 + (lg << 2) + r;
                    int cb2 = (nf * 16 + lr) * 2;
                    *(unsigned short*)(p_lds + swz128(row, cb2)) = f2bf(s[i][nf][r]);
                }
        asm volatile("s_waitcnt lgkmcnt(0)" ::: "memory");
        short8 pa[2][2];
#pragma unroll
        for (int i = 0; i < 2; i++)
#pragma unroll
            for (int kf = 0; kf < 2; kf++)
                pa[i][kf] = *(const short8*)(p_lds + swz128(i * 16 + lr, kf * 64 + lg * 16));
        short8 vb[8][2];
#pragma unroll
        for (int nf = 0; nf < 8; nf++)
#pragma unroll
            for (int kf = 0; kf < 2; kf++)
                vb[nf][kf] = *(const short8*)&Vt[(size_t)(nf * 16 + lr) * 2048 + sb + kf * 32 + lg * 8];
#pragma unroll
        for (int i = 0; i < 2; i++)
#pragma unroll
            for (int nf = 0; nf < 8; nf++)
#pragma unroll
                for (int kf = 0; kf < 2; kf++)
                    o[i][nf] = __builtin_amdgcn_mfma_f32_16x16x32_bf16(pa[i][kf], vb[nf][kf], o[i][nf], 0, 0, 0);
    }
#pragma unroll
    for (int i = 0; i < 2; i++)
#pragma unroll
        for (int r = 0; r < 4; r++) {
            int q = i * 16 + (lg << 2) + r;
            ml[w][0][q] = mrow[i][r];
            ml[w][1][q] = lrow[i][r];
        }
    asm volatile("s_waitcnt lgkmcnt(0)" ::: "memory");
#pragma unroll
    for (int i = 0; i < 2; i++)
#pragma unroll
        for (int jn = 0; jn < 8; jn++)
#pragma unroll
            for (int r = 0; r < 4; r++)
                o_lds[w][i * 16 + (lg << 2) + r][jn * 16 + lr] = o[i][jn][r];
    __syncthreads();
    int q = tid >> 3, h0 = (tid & 7) << 4;
    float mg = fmaxf(fmaxf(ml[0][0][q], ml[1][0][q]), fmaxf(ml[2][0][q], ml[3][0][q]));
    float scw[4], den = 0.f;
#pragma unroll
    for (int w4 = 0; w4 < 4; w4++) {
        scw[w4] = __expf(ml[w4][0][q] - mg);
        den += scw[w4] * ml[w4][1][q];
    }
    float inv = 1.0f / den;
    float* op = out + ((size_t)b * 2048 + qbase + q) * 128 + h0;
#pragma unroll
    for (int jj = 0; jj < 4; jj++) {
        f32x4 a4 = (f32x4){0.f, 0.f, 0.f, 0.f};
#pragma unroll
        for (int w4 = 0; w4 < 4; w4++) {
            f32x4 v = *(const f32x4*)&o_lds[w4][q][h0 + jj * 4];
            a4 += scw[w4] * v;
        }
        a4 *= inv;
        *(f32x4*)(op + jj * 4) = a4;
    }
}

extern "C" void kernel_launch(void* const* d_in, const int* in_sizes, int n_in,
                              void* d_out, int out_size, void* d_ws, size_t ws_size,
                              hipStream_t stream) {
    (void)in_sizes; (void)n_in; (void)out_size; (void)ws_size;
    const float* x  = (const float*)d_in[0];
    const float* Wq = (const float*)d_in[1];
    const float* bq = (const float*)d_in[2];
    const float* Wk = (const float*)d_in[3];
    const float* bk = (const float*)d_in[4];
    const float* Wv = (const float*)d_in[5];
    const float* bv = (const float*)d_in[6];
    unsigned short* ws = (unsigned short*)d_ws;
    float* out = (float*)d_out;

    wt_kernel<<<96, 256, 0, stream>>>(Wq, Wk, Wv, ws);
    qkv_kernel<<<768, 256, 0, stream>>>(x, bq, bk, bv, ws);
    attn_kernel<<<dim3(8, 64), 256, 0, stream>>>(ws, out);
}